// Round 2
// baseline (937.731 us; speedup 1.0000x reference)
//
#include <hip/hip_runtime.h>

// 2-layer GRU (reset_after, sigmoid gates, linear act, no bias) + Wout.
// B=16384, T=25, D=128. 256 blocks x 1024 threads (16 waves); block owns 64
// batch rows. Waves 0-7 = layer1 @ step it, waves 8-15 = layer2 @ step it-1.
// FLIPPED MFMA operands: weights = A operand (24 frags = 96 VGPRs), data = B
// operand streamed k-by-k from LDS. amdgpu_waves_per_eu(4,4) pins the
// register budget at 128/wave so the allocator cannot undershoot and spill
// the weights.
//
// ROUND 2: x is staged into LDS as *f16 via registers* with a full-timestep
// prefetch (round 1 proved direct per-nt global reads expose ~200cy L2
// latency: dur 293->408us, MfmaUtil 23->16). Each thread loads 8 f32 of
// x(t+1) at iteration top (coalesced 512B rows), converts with 4 pkrtz and
// ds_write_b128 at iteration bottom after compute -> latency hidden under
// the whole compute phase like round-0's DMA, but: X LDS reads halve
// (f16 vs f32), conversion happens once per element instead of once per
// consuming wave (8x), layer-1's inner loop becomes identical to layer-2's,
// and the global_load_lds vmcnt(0) barrier drain is gone. LDS 137->104 KB.
// C/D = [d-col][batch]: h_prev re-read is 1 ds_read_b64, h write 1 b64.

typedef _Float16 half8 __attribute__((ext_vector_type(8)));
typedef __fp16  fp16x2 __attribute__((ext_vector_type(2)));
typedef __fp16  fp16x4 __attribute__((ext_vector_type(4)));
typedef float    f32x4 __attribute__((ext_vector_type(4)));

#define MFMA(a, b, c) __builtin_amdgcn_mfma_f32_16x16x32_f16((a), (b), (c), 0, 0, 0)

constexpr int T_STEPS = 25;
constexpr int D = 128;
constexpr int NG = 384;   // 3*D
constexpr int BT = 64;    // batch rows per block
constexpr int SH = 136;   // f16 row stride: 272 B == 16 mod 128 -> benign on b128

__device__ __forceinline__ float sigm(float v) {
    return __builtin_amdgcn_rcpf(1.0f + __expf(-v));
}

__device__ __forceinline__ half8 pkrtz8(const f32x4 v0, const f32x4 v1) {
    union { fp16x2 h2[4]; half8 h8; } u;
    u.h2[0] = __builtin_amdgcn_cvt_pkrtz(v0.x, v0.y);
    u.h2[1] = __builtin_amdgcn_cvt_pkrtz(v0.z, v0.w);
    u.h2[2] = __builtin_amdgcn_cvt_pkrtz(v1.x, v1.y);
    u.h2[3] = __builtin_amdgcn_cvt_pkrtz(v1.z, v1.w);
    return u.h8;
}

__global__ __attribute__((amdgpu_flat_work_group_size(1024, 1024),
                          amdgpu_waves_per_eu(4, 4)))
void gru2_kernel(
    const float* __restrict__ x, const float* __restrict__ W1,
    const float* __restrict__ U1, const float* __restrict__ W2,
    const float* __restrict__ U2, const float* __restrict__ Wout,
    float* __restrict__ out) {
    __shared__ _Float16 H1[2][BT * SH];  // h1 state, double-buffered (34.8 KB)
    __shared__ _Float16 H2[2][BT * SH];  // h2 state, double-buffered (34.8 KB)
    __shared__ _Float16 XH[2][BT * SH];  // x_t as f16, double-buffered (34.8 KB)

    const int tid = threadIdx.x;
    const int w = tid >> 6, lane = tid & 63, l15 = lane & 15, quad = lane >> 4;
    const int layer = w >> 3;       // 0: layer1 waves, 1: layer2 waves
    const int d0 = (w & 7) * 16;    // this wave's 16-col d-slice per gate
    const int b0 = blockIdx.x * BT;

    // staging assignment: thread -> (row, 8-col chunk) of the 64x128 x tile
    const int srow = tid >> 4;           // 0..63
    const int scol = (tid & 15) * 8;     // 0..120
    const float* xsrc = x + ((size_t)(b0 + srow) * T_STEPS) * D + scol;

    // ---- one-time: this wave's [W;U] fragments as MFMA *A* operand ----
    // A-frag (16x16x32): lane holds A[m = l15][k = quad*8 + e]; element =
    // Wgt[k][gate*128 + d0 + l15]. k-tiles 0..3 = W rows, 4..7 = U rows.
    half8 wg[3][8];
    {
        const float* Wp = layer ? W2 : W1;
        const float* Up = layer ? U2 : U1;
#pragma unroll
        for (int g = 0; g < 3; ++g) {
            const int c = g * 128 + d0 + l15;
#pragma unroll
            for (int kt = 0; kt < 8; ++kt) {
                const float* src = (kt < 4 ? Wp : Up) + (size_t)((kt & 3) * 32 + quad * 8) * NG + c;
                half8 f;
#pragma unroll
                for (int e = 0; e < 8; ++e) f[e] = (_Float16)src[(size_t)e * NG];
                wg[g][kt] = f;
            }
        }
    }

    // zero initial states: L1 reads H1[0] at iter 0; L2 reads H2[1] at iter 1
    for (int idx = tid; idx < BT * SH; idx += 1024) {
        H1[0][idx] = (_Float16)0.f;
        H2[1][idx] = (_Float16)0.f;
    }
    // prologue: stage x(t=0) into XH[0] (f32 load -> pkrtz -> f16 LDS)
    {
        const f32x4 v0 = *(const f32x4*)(xsrc + 0);
        const f32x4 v1 = *(const f32x4*)(xsrc + 4);
        *(half8*)&XH[0][srow * SH + scol] = pkrtz8(v0, v1);
    }
    __syncthreads();

#pragma unroll 1
    for (int it = 0; it <= T_STEPS; ++it) {
        const int p = it & 1, q = p ^ 1;
        // prefetch x(it+1) into registers; conversion+LDS write happens after
        // compute, so the ~200-900cy VMEM latency hides under the MFMA phase.
        f32x4 xa, xb;
        const bool stage = (it + 1 < T_STEPS);
        if (stage) {
            const float* px = xsrc + (size_t)(it + 1) * D;
            xa = *(const f32x4*)(px + 0);
            xb = *(const f32x4*)(px + 4);
        }
        const bool active = layer ? (it >= 1) : (it < T_STEPS);
        if (active) {
            const _Float16* Hst = layer ? H2[p] : H1[p];  // own state (h_prev)
            _Float16* Hout      = layer ? H2[q] : H1[q];  // own state dest
            const _Float16* Hin = layer ? H1[p] : XH[p];  // input: h1 or x_t
#pragma unroll
            for (int nt = 0; nt < 4; ++nt) {
                const int bb = nt * 16 + l15;             // batch row (B-frag n)
                f32x4 cz = {0.f, 0.f, 0.f, 0.f}, cr = {0.f, 0.f, 0.f, 0.f};
                f32x4 cxh = {0.f, 0.f, 0.f, 0.f}, cuh = {0.f, 0.f, 0.f, 0.f};
                {
                    const _Float16* bi = Hin + bb * SH + quad * 8;
#pragma unroll
                    for (int kt = 0; kt < 4; ++kt) {  // input part (W)
                        const half8 B = *(const half8*)(bi + kt * 32);
                        cz  = MFMA(wg[0][kt], B, cz);
                        cr  = MFMA(wg[1][kt], B, cr);
                        cxh = MFMA(wg[2][kt], B, cxh);
                    }
                }
                {
                    const _Float16* bs = Hst + bb * SH + quad * 8;
#pragma unroll
                    for (int kt = 0; kt < 4; ++kt) {  // state part (U): h_prev
                        const half8 B = *(const half8*)(bs + kt * 32);
                        cz  = MFMA(wg[0][4 + kt], B, cz);
                        cr  = MFMA(wg[1][4 + kt], B, cr);
                        cuh = MFMA(wg[2][4 + kt], B, cuh);
                    }
                }
                // C/D: col(N)=l15 -> batch bb; row(M)=quad*4+i2 -> d0+quad*4+i2
                const int hoff = bb * SH + d0 + quad * 4;
                const fp16x4 hp4 = *(const fp16x4*)(Hst + hoff);
                fp16x4 hn4;
#pragma unroll
                for (int i2 = 0; i2 < 4; ++i2) {
                    const float z = sigm(cz[i2]);
                    const float r = sigm(cr[i2]);
                    const float hh = cxh[i2] + r * cuh[i2];
                    hn4[i2] = (__fp16)(hh + z * ((float)hp4[i2] - hh));
                }
                *(fp16x4*)(Hout + hoff) = hn4;
            }
        }
        // write-late: convert and store x(it+1) into XH[q]. Readers of XH[q]
        // finished at the barrier that ended iter it-1.
        if (stage) {
            *(half8*)&XH[q][srow * SH + scol] = pkrtz8(xa, xb);
        }
        __syncthreads();
    }

    // ---- epilogue: out = h2(T-1) @ Wout; h2 is in H2[0]. Flipped operands:
    // A = Wout^T (regs), B = h2 (LDS). Waves 8-15, 16 out-cols each.
    if (layer) {
        half8 wO[4];
#pragma unroll
        for (int kt = 0; kt < 4; ++kt) {
            half8 f;
#pragma unroll
            for (int e = 0; e < 8; ++e)
                f[e] = (_Float16)Wout[(size_t)(kt * 32 + quad * 8 + e) * D + d0 + l15];
            wO[kt] = f;
        }
#pragma unroll
        for (int nt = 0; nt < 4; ++nt) {
            const _Float16* bp = H2[0] + (nt * 16 + l15) * SH + quad * 8;
            f32x4 acc = {0.f, 0.f, 0.f, 0.f};
#pragma unroll
            for (int kt = 0; kt < 4; ++kt)
                acc = MFMA(wO[kt], *(const half8*)(bp + kt * 32), acc);
            *(f32x4*)(out + (size_t)(b0 + nt * 16 + l15) * D + d0 + quad * 4) = acc;
        }
    }
}

extern "C" void kernel_launch(void* const* d_in, const int* in_sizes, int n_in,
                              void* d_out, int out_size, void* d_ws, size_t ws_size,
                              hipStream_t stream) {
    const float* x    = (const float*)d_in[0];
    const float* W1   = (const float*)d_in[1];
    const float* U1   = (const float*)d_in[2];
    const float* W2   = (const float*)d_in[3];
    const float* U2   = (const float*)d_in[4];
    const float* Wout = (const float*)d_in[5];
    gru2_kernel<<<dim3(16384 / BT), dim3(1024), 0, stream>>>(
        x, W1, U1, W2, U2, Wout, (float*)d_out);
}

// Round 3
// 846.361 us; speedup vs baseline: 1.1080x; 1.1080x over previous
//
#include <hip/hip_runtime.h>

// 2-layer GRU (reset_after, sigmoid gates, linear act, no bias) + Wout.
// B=16384, T=25, D=128. 256 blocks x 1024 threads (16 waves); block owns 64
// batch rows. Waves 0-7 = layer1 @ step it, waves 8-15 = layer2 @ step it-1.
// FLIPPED MFMA operands: weights = A operand (24 frags = 96 VGPRs), data = B
// operand streamed from LDS. amdgpu_waves_per_eu(4,4) pins the register
// budget at 128/wave.
//
// ROUND 3 (clock-corrected model: chip runs ~0.7 GHz here; LDS pipe was
// ~95% of the 8k-cycle timestep -> LDS-throughput-bound):
//  * X staged in LDS as f16 via short-lifetime registers (load->pkrtz->
//    ds_write adjacent; round 2 proved holding 8 f32 across compute spills
//    ~1.9 GB of scratch). X LDS reads halve (128 vs 256 b128/CU-iter),
//    conversion once per element (was 8x/wave), DMA vmcnt-drain gone.
//  * Stage parity-split: waves (w>>2)&1==0 stage at iter top, others after
//    compute -> each SIMD has 2 waves computing while 2 stall on VMEM.
//  * All LDS buffers XOR-swizzled at 16B-chunk granularity
//    (phys_chunk = (byte>>4) ^ (row&15), row stride 128 f16, no pad):
//    every b128 read lands exactly 4 lanes/chunk (wave64 minimum),
//    b64 h-path 2 rows x 16B/chunk -> zero excess bank conflicts.
//    LDS total 96 KB (XH/H1/H2 double-buffered, 16 KB each).
// C/D = [d-col][batch]: h_prev re-read is 1 b64, h write 1 b64.

typedef _Float16 half8 __attribute__((ext_vector_type(8)));
typedef __fp16  fp16x2 __attribute__((ext_vector_type(2)));
typedef __fp16  fp16x4 __attribute__((ext_vector_type(4)));
typedef float    f32x4 __attribute__((ext_vector_type(4)));

#define MFMA(a, b, c) __builtin_amdgcn_mfma_f32_16x16x32_f16((a), (b), (c), 0, 0, 0)

constexpr int T_STEPS = 25;
constexpr int D = 128;
constexpr int NG = 384;   // 3*D
constexpr int BT = 64;    // batch rows per block

__device__ __forceinline__ float sigm(float v) {
    return __builtin_amdgcn_rcpf(1.0f + __expf(-v));
}

__device__ __forceinline__ half8 pkrtz8(const f32x4 v0, const f32x4 v1) {
    union { fp16x2 h2[4]; half8 h8; } u;
    u.h2[0] = __builtin_amdgcn_cvt_pkrtz(v0.x, v0.y);
    u.h2[1] = __builtin_amdgcn_cvt_pkrtz(v0.z, v0.w);
    u.h2[2] = __builtin_amdgcn_cvt_pkrtz(v1.x, v1.y);
    u.h2[3] = __builtin_amdgcn_cvt_pkrtz(v1.z, v1.w);
    return u.h8;
}

__global__ __attribute__((amdgpu_flat_work_group_size(1024, 1024),
                          amdgpu_waves_per_eu(4, 4)))
void gru2_kernel(
    const float* __restrict__ x, const float* __restrict__ W1,
    const float* __restrict__ U1, const float* __restrict__ W2,
    const float* __restrict__ U2, const float* __restrict__ Wout,
    float* __restrict__ out) {
    __shared__ _Float16 H1[2][BT * D];  // h1 state, double-buffered (2x16 KB)
    __shared__ _Float16 H2[2][BT * D];  // h2 state, double-buffered (2x16 KB)
    __shared__ _Float16 XH[2][BT * D];  // x_t as f16, double-buffered (2x16 KB)

    const int tid = threadIdx.x;
    const int w = tid >> 6, lane = tid & 63, l15 = lane & 15, quad = lane >> 4;
    const int layer = w >> 3;       // 0: layer1 waves, 1: layer2 waves
    const int d0 = (w & 7) * 16;    // this wave's 16-col d-slice per gate
    const int b0 = blockIdx.x * BT;

    // loop-invariant swizzled chunk offsets (f16 units) for the 4 kt b128
    // reads: byte chunk (quad + 4*kt), XOR'd with row&15 (row = nt*16+l15,
    // so row&15 == l15 always).
    int xc[4];
#pragma unroll
    for (int kt = 0; kt < 4; ++kt) xc[kt] = ((quad + 4 * kt) ^ l15) << 3;
    // swizzled f16-offset (within row) of this lane's 8B h-slot
    const int hoffc = (((((d0 >> 3) + (quad >> 1)) ^ l15)) << 3) + (quad & 1) * 4;

    // x staging: thread -> (row srow, 16B chunk schunk) of the 64x128 tile
    const int srow = tid >> 4;          // 0..63
    const int schunk = tid & 15;        // 0..15
    const float* xsrc = x + (size_t)(b0 + srow) * T_STEPS * D + schunk * 8;
    const int sidx = srow * D + ((schunk ^ (srow & 15)) << 3);
    const bool early = ((w >> 2) & 1) == 0;  // per-SIMD: 2 early, 2 late waves

    // ---- one-time: this wave's [W;U] fragments as MFMA *A* operand ----
    // A-frag (16x16x32): lane holds A[m = l15][k = quad*8 + e]; element =
    // Wgt[k][gate*128 + d0 + l15]. k-tiles 0..3 = W rows, 4..7 = U rows.
    half8 wg[3][8];
    {
        const float* Wp = layer ? W2 : W1;
        const float* Up = layer ? U2 : U1;
#pragma unroll
        for (int g = 0; g < 3; ++g) {
            const int c = g * 128 + d0 + l15;
#pragma unroll
            for (int kt = 0; kt < 8; ++kt) {
                const float* src = (kt < 4 ? Wp : Up) + (size_t)((kt & 3) * 32 + quad * 8) * NG + c;
                half8 f;
#pragma unroll
                for (int e = 0; e < 8; ++e) f[e] = (_Float16)src[(size_t)e * NG];
                wg[g][kt] = f;
            }
        }
    }

    // zero initial states: L1 reads H1[0] at iter 0; L2 reads H2[1] at iter 1
    for (int idx = tid; idx < BT * D; idx += 1024) {
        H1[0][idx] = (_Float16)0.f;
        H2[1][idx] = (_Float16)0.f;
    }
    // prologue: stage x(t=0) into XH[0] (f32 load -> pkrtz -> swizzled f16)
    {
        const f32x4 v0 = *(const f32x4*)(xsrc + 0);
        const f32x4 v1 = *(const f32x4*)(xsrc + 4);
        *(half8*)&XH[0][sidx] = pkrtz8(v0, v1);
    }
    __syncthreads();

#pragma unroll 1
    for (int it = 0; it <= T_STEPS; ++it) {
        const int p = it & 1, q = p ^ 1;
        const bool stage = (it + 1 < T_STEPS);
        // early waves: stage x(it+1) -> XH[q] now (their VMEM stall overlaps
        // the late waves' compute on the same SIMD). Load/convert/store are
        // adjacent: no registers live across the compute phase.
        if (stage && early) {
            const float* px = xsrc + (size_t)(it + 1) * D;
            *(half8*)&XH[q][sidx] =
                pkrtz8(*(const f32x4*)px, *(const f32x4*)(px + 4));
        }
        const bool active = layer ? (it >= 1) : (it < T_STEPS);
        if (active) {
            const _Float16* Hst = layer ? H2[p] : H1[p];  // own state (h_prev)
            _Float16* Hout      = layer ? H2[q] : H1[q];  // own state dest
            const _Float16* Hin = layer ? H1[p] : XH[p];  // input: h1 or x_t
#pragma unroll
            for (int nt = 0; nt < 4; ++nt) {
                const int bb = nt * 16 + l15;             // batch row (B-frag n)
                const int rowb = (nt * 16 + l15) * D;     // row base (f16 idx)
                f32x4 cz = {0.f, 0.f, 0.f, 0.f}, cr = {0.f, 0.f, 0.f, 0.f};
                f32x4 cxh = {0.f, 0.f, 0.f, 0.f}, cuh = {0.f, 0.f, 0.f, 0.f};
                {
                    const _Float16* bi = Hin + rowb;
#pragma unroll
                    for (int kt = 0; kt < 4; ++kt) {  // input part (W)
                        const half8 B = *(const half8*)(bi + xc[kt]);
                        cz  = MFMA(wg[0][kt], B, cz);
                        cr  = MFMA(wg[1][kt], B, cr);
                        cxh = MFMA(wg[2][kt], B, cxh);
                    }
                }
                {
                    const _Float16* bs = Hst + rowb;
#pragma unroll
                    for (int kt = 0; kt < 4; ++kt) {  // state part (U): h_prev
                        const half8 B = *(const half8*)(bs + xc[kt]);
                        cz  = MFMA(wg[0][4 + kt], B, cz);
                        cr  = MFMA(wg[1][4 + kt], B, cr);
                        cuh = MFMA(wg[2][4 + kt], B, cuh);
                    }
                }
                // C/D: col(N)=l15 -> batch bb; row(M)=quad*4+i2 -> d0+quad*4+i2
                const int hoff = rowb + hoffc;
                const fp16x4 hp4 = *(const fp16x4*)(Hst + hoff);
                fp16x4 hn4;
#pragma unroll
                for (int i2 = 0; i2 < 4; ++i2) {
                    const float z = sigm(cz[i2]);
                    const float r = sigm(cr[i2]);
                    const float hh = cxh[i2] + r * cuh[i2];
                    hn4[i2] = (__fp16)(hh + z * ((float)hp4[i2] - hh));
                }
                *(fp16x4*)(Hout + hoff) = hn4;
            }
        }
        // late waves: stage x(it+1) now; their earlier compute overlapped the
        // early waves' VMEM stall.
        if (stage && !early) {
            const float* px = xsrc + (size_t)(it + 1) * D;
            *(half8*)&XH[q][sidx] =
                pkrtz8(*(const f32x4*)px, *(const f32x4*)(px + 4));
        }
        __syncthreads();
    }

    // ---- epilogue: out = h2(T-1) @ Wout; h2 is in H2[0]. Flipped operands:
    // A = Wout^T (regs), B = h2 (LDS, swizzled). Waves 8-15, 16 out-cols each.
    if (layer) {
        half8 wO[4];
#pragma unroll
        for (int kt = 0; kt < 4; ++kt) {
            half8 f;
#pragma unroll
            for (int e = 0; e < 8; ++e)
                f[e] = (_Float16)Wout[(size_t)(kt * 32 + quad * 8 + e) * D + d0 + l15];
            wO[kt] = f;
        }
#pragma unroll
        for (int nt = 0; nt < 4; ++nt) {
            const _Float16* bp = H2[0] + (nt * 16 + l15) * D;
            f32x4 acc = {0.f, 0.f, 0.f, 0.f};
#pragma unroll
            for (int kt = 0; kt < 4; ++kt)
                acc = MFMA(wO[kt], *(const half8*)(bp + xc[kt]), acc);
            *(f32x4*)(out + (size_t)(b0 + nt * 16 + l15) * D + d0 + quad * 4) = acc;
        }
    }
}

extern "C" void kernel_launch(void* const* d_in, const int* in_sizes, int n_in,
                              void* d_out, int out_size, void* d_ws, size_t ws_size,
                              hipStream_t stream) {
    const float* x    = (const float*)d_in[0];
    const float* W1   = (const float*)d_in[1];
    const float* U1   = (const float*)d_in[2];
    const float* W2   = (const float*)d_in[3];
    const float* U2   = (const float*)d_in[4];
    const float* Wout = (const float*)d_in[5];
    gru2_kernel<<<dim3(16384 / BT), dim3(1024), 0, stream>>>(
        x, W1, U1, W2, U2, Wout, (float*)d_out);
}

// Round 4
// 842.839 us; speedup vs baseline: 1.1126x; 1.0042x over previous
//
#include <hip/hip_runtime.h>

// 2-layer GRU (reset_after, sigmoid gates, linear act, no bias) + Wout.
// B=16384, T=25, D=128. 256 blocks x 1024 threads (16 waves); block owns 64
// batch rows. Waves 0-7 = layer1 @ step it, waves 8-15 = layer2 @ step it-1.
// FLIPPED MFMA operands: weights = A operand (24 frags = 96 VGPRs), data = B
// operand streamed from LDS. amdgpu_waves_per_eu(4,4) pins 128 regs/wave.
//
// ROUND 4: register budget is razor-thin (96 weight regs; round 2/3 proved
// +8 persistent VGPRs spills the weight array -> 1.9 GB scratch re-reads,
// FETCH_SIZE is the canary). So conflict-freedom must cost ZERO registers:
// every 64x128 f16 LDS tile is stored KT-MAJOR as [4 kt][64 rows][32 f16].
// A b128 frag read (row, quad) hits byte kt*4096 + row*64 + quad*16 ->
// across 64 lanes each dword-bank gets exactly 8 accesses = b128 minimum,
// conflict-free with NO swizzle; kt becomes a ds_read offset: immediate.
// Staging writes are likewise exactly-minimum. Only the b64 h-slot path is
// 2-way (~free, m136). Kept from round 3: X staged as f16 via short-lifetime
// registers (X frag reads halve; pkrtz once per element instead of 8x/wave;
// no DMA vmcnt(0) drain), early/late stage parity split (2 waves/SIMD stage
// before compute, 2 after -> VMEM stall overlaps compute). Staging address
// is a 32-bit int voffset against an SGPR base (saves the 64-bit pointer).
// C/D = [d-col][batch]: h_prev re-read is 1 b64, h write 1 b64.

typedef _Float16 half8 __attribute__((ext_vector_type(8)));
typedef __fp16  fp16x2 __attribute__((ext_vector_type(2)));
typedef __fp16  fp16x4 __attribute__((ext_vector_type(4)));
typedef float    f32x4 __attribute__((ext_vector_type(4)));

#define MFMA(a, b, c) __builtin_amdgcn_mfma_f32_16x16x32_f16((a), (b), (c), 0, 0, 0)

constexpr int T_STEPS = 25;
constexpr int D = 128;
constexpr int NG = 384;   // 3*D
constexpr int BT = 64;    // batch rows per block
constexpr int KTP = 64 * 32;  // one kt-plane: 64 rows x 32 f16 = 2048 f16 (4 KB)

__device__ __forceinline__ float sigm(float v) {
    return __builtin_amdgcn_rcpf(1.0f + __expf(-v));
}

__device__ __forceinline__ half8 pkrtz8(const f32x4 v0, const f32x4 v1) {
    union { fp16x2 h2[4]; half8 h8; } u;
    u.h2[0] = __builtin_amdgcn_cvt_pkrtz(v0.x, v0.y);
    u.h2[1] = __builtin_amdgcn_cvt_pkrtz(v0.z, v0.w);
    u.h2[2] = __builtin_amdgcn_cvt_pkrtz(v1.x, v1.y);
    u.h2[3] = __builtin_amdgcn_cvt_pkrtz(v1.z, v1.w);
    return u.h8;
}

__global__ __attribute__((amdgpu_flat_work_group_size(1024, 1024),
                          amdgpu_waves_per_eu(4, 4)))
void gru2_kernel(
    const float* __restrict__ x, const float* __restrict__ W1,
    const float* __restrict__ U1, const float* __restrict__ W2,
    const float* __restrict__ U2, const float* __restrict__ Wout,
    float* __restrict__ out) {
    __shared__ _Float16 H1[2][4 * KTP];  // h1 state, kt-major, dbuf (2x16 KB)
    __shared__ _Float16 H2[2][4 * KTP];  // h2 state, kt-major, dbuf (2x16 KB)
    __shared__ _Float16 XH[2][4 * KTP];  // x_t f16, kt-major, dbuf (2x16 KB)

    const int tid = threadIdx.x;
    const int w = tid >> 6, lane = tid & 63, l15 = lane & 15, quad = lane >> 4;
    const int layer = w >> 3;       // 0: layer1 waves, 1: layer2 waves
    const int d0 = (w & 7) * 16;    // this wave's 16-col d-slice per gate
    const int b0 = blockIdx.x * BT;

    // element (row, col) lives at (col>>5)*KTP + row*32 + (col&31).
    // h-slot (row, d0 + quad*4): per-wave/lane constant part:
    const int hbase = (d0 >> 5) * KTP + (d0 & 16) + quad * 4;

    // x staging: thread -> (row srow, 16B chunk schunk) of the 64x128 tile
    const int srow = tid >> 4;          // 0..63
    const int schunk = tid & 15;        // 0..15
    const int sidx = (schunk >> 2) * KTP + srow * 32 + (schunk & 3) * 8;
    const int xvo = srow * T_STEPS * D + schunk * 8;  // 32-bit voffset (f32)
    const float* xb = x + (size_t)b0 * T_STEPS * D;   // uniform (SGPR) base
    const bool early = ((w >> 2) & 1) == 0;  // per-SIMD: 2 early, 2 late

    // ---- one-time: this wave's [W;U] fragments as MFMA *A* operand ----
    // A-frag (16x16x32): lane holds A[m = l15][k = quad*8 + e]; element =
    // Wgt[k][gate*128 + d0 + l15]. k-tiles 0..3 = W rows, 4..7 = U rows.
    half8 wg[3][8];
    {
        const float* Wp = layer ? W2 : W1;
        const float* Up = layer ? U2 : U1;
#pragma unroll
        for (int g = 0; g < 3; ++g) {
            const int c = g * 128 + d0 + l15;
#pragma unroll
            for (int kt = 0; kt < 8; ++kt) {
                const float* src = (kt < 4 ? Wp : Up) + (size_t)((kt & 3) * 32 + quad * 8) * NG + c;
                half8 f;
#pragma unroll
                for (int e = 0; e < 8; ++e) f[e] = (_Float16)src[(size_t)e * NG];
                wg[g][kt] = f;
            }
        }
    }

    // zero initial states: L1 reads H1[0] at iter 0; L2 reads H2[1] at iter 1
    for (int idx = tid; idx < 4 * KTP; idx += 1024) {
        H1[0][idx] = (_Float16)0.f;
        H2[1][idx] = (_Float16)0.f;
    }
    // prologue: stage x(t=0) into XH[0] (f32 load -> pkrtz -> kt-major f16)
    {
        const float* px = xb + xvo;
        *(half8*)&XH[0][sidx] = pkrtz8(*(const f32x4*)px, *(const f32x4*)(px + 4));
    }
    __syncthreads();

#pragma unroll 1
    for (int it = 0; it <= T_STEPS; ++it) {
        const int p = it & 1, q = p ^ 1;
        const bool stage = (it + 1 < T_STEPS);
        // early waves stage x(it+1) now: their VMEM stall overlaps the late
        // waves' compute on the same SIMD. Load/convert/store adjacent: no
        // registers live across the compute phase.
        if (stage && early) {
            const float* px = xb + (xvo + (it + 1) * D);
            *(half8*)&XH[q][sidx] =
                pkrtz8(*(const f32x4*)px, *(const f32x4*)(px + 4));
        }
        const bool active = layer ? (it >= 1) : (it < T_STEPS);
        if (active) {
            const _Float16* Hst = layer ? H2[p] : H1[p];  // own state (h_prev)
            _Float16* Hout      = layer ? H2[q] : H1[q];  // own state dest
            const _Float16* Hin = layer ? H1[p] : XH[p];  // input: h1 or x_t
#pragma unroll
            for (int nt = 0; nt < 4; ++nt) {
                const int rowb = (nt * 16 + l15) * 32;    // row base (f16)
                f32x4 cz = {0.f, 0.f, 0.f, 0.f}, cr = {0.f, 0.f, 0.f, 0.f};
                f32x4 cxh = {0.f, 0.f, 0.f, 0.f}, cuh = {0.f, 0.f, 0.f, 0.f};
                {
                    const _Float16* bi = Hin + rowb + quad * 8;
#pragma unroll
                    for (int kt = 0; kt < 4; ++kt) {  // input part (W)
                        const half8 B = *(const half8*)(bi + kt * KTP);
                        cz  = MFMA(wg[0][kt], B, cz);
                        cr  = MFMA(wg[1][kt], B, cr);
                        cxh = MFMA(wg[2][kt], B, cxh);
                    }
                }
                {
                    const _Float16* bs = Hst + rowb + quad * 8;
#pragma unroll
                    for (int kt = 0; kt < 4; ++kt) {  // state part (U): h_prev
                        const half8 B = *(const half8*)(bs + kt * KTP);
                        cz  = MFMA(wg[0][4 + kt], B, cz);
                        cr  = MFMA(wg[1][4 + kt], B, cr);
                        cuh = MFMA(wg[2][4 + kt], B, cuh);
                    }
                }
                // C/D: col(N)=l15 -> batch; row(M)=quad*4+i2 -> d0+quad*4+i2
                const int hoff = rowb + hbase;
                const fp16x4 hp4 = *(const fp16x4*)(Hst + hoff);
                fp16x4 hn4;
#pragma unroll
                for (int i2 = 0; i2 < 4; ++i2) {
                    const float z = sigm(cz[i2]);
                    const float r = sigm(cr[i2]);
                    const float hh = cxh[i2] + r * cuh[i2];
                    hn4[i2] = (__fp16)(hh + z * ((float)hp4[i2] - hh));
                }
                *(fp16x4*)(Hout + hoff) = hn4;
            }
        }
        // late waves stage x(it+1) now; their compute overlapped the early
        // waves' VMEM stall.
        if (stage && !early) {
            const float* px = xb + (xvo + (it + 1) * D);
            *(half8*)&XH[q][sidx] =
                pkrtz8(*(const f32x4*)px, *(const f32x4*)(px + 4));
        }
        __syncthreads();
    }

    // ---- epilogue: out = h2(T-1) @ Wout; h2 is in H2[0] (kt-major).
    // Flipped operands: A = Wout^T (regs), B = h2 frags. Waves 8-15.
    if (layer) {
        half8 wO[4];
#pragma unroll
        for (int kt = 0; kt < 4; ++kt) {
            half8 f;
#pragma unroll
            for (int e = 0; e < 8; ++e)
                f[e] = (_Float16)Wout[(size_t)(kt * 32 + quad * 8 + e) * D + d0 + l15];
            wO[kt] = f;
        }
#pragma unroll
        for (int nt = 0; nt < 4; ++nt) {
            const _Float16* bp = H2[0] + (nt * 16 + l15) * 32 + quad * 8;
            f32x4 acc = {0.f, 0.f, 0.f, 0.f};
#pragma unroll
            for (int kt = 0; kt < 4; ++kt)
                acc = MFMA(wO[kt], *(const half8*)(bp + kt * KTP), acc);
            *(f32x4*)(out + (size_t)(b0 + nt * 16 + l15) * D + d0 + quad * 4) = acc;
        }
    }
}

extern "C" void kernel_launch(void* const* d_in, const int* in_sizes, int n_in,
                              void* d_out, int out_size, void* d_ws, size_t ws_size,
                              hipStream_t stream) {
    const float* x    = (const float*)d_in[0];
    const float* W1   = (const float*)d_in[1];
    const float* U1   = (const float*)d_in[2];
    const float* W2   = (const float*)d_in[3];
    const float* U2   = (const float*)d_in[4];
    const float* Wout = (const float*)d_in[5];
    gru2_kernel<<<dim3(16384 / BT), dim3(1024), 0, stream>>>(
        x, W1, U1, W2, U2, Wout, (float*)d_out);
}

// Round 5
// 547.557 us; speedup vs baseline: 1.7126x; 1.5393x over previous
//
#include <hip/hip_runtime.h>

// 2-layer GRU (reset_after, sigmoid gates, linear act, no bias) + Wout.
// B=16384, T=25, D=128. 256 blocks x 1024 threads (16 waves); block owns 64
// batch rows. Waves 0-7 = layer1 @ step it, waves 8-15 = layer2 @ step it-1.
// FLIPPED MFMA operands: weights = A operand (24 frags = 96 VGPRs), data = B
// operand streamed from LDS. NO asm pinning. amdgpu_waves_per_eu(4,4) pins
// the register budget at 128/wave.
//
// ROUND 5: structure is round-0 VERBATIM (f32 X DMA double-buffer at SX=132,
// per-wave pkrtz, identical staging loops & register footprint -- rounds 2-4
// proved ANY structural change to staging makes the allocator drop the
// weight array: 1.8-1.9 GB of per-use HBM re-reads, FETCH_SIZE canary).
// The ONLY change: H1/H2 use the round-3-proven conflict-free mapping
//   phys(row,col) = row*128 + (((col>>3) ^ (row&15)) << 3) + (col&7)
// (XOR of the 16B-chunk index with row&15; measured 1.6e6 conflicts vs
// 1.16e7 for the SH=136 pad in round 1). Since quad+4kt == quad^(4kt) and
// rowb occupies bits >=7, each kt fragment read is
//   (rowb + ((quad^l15)<<3)) ^ (kt*32)
// -- a transient v_xor with an inline constant, ZERO persistent registers
// (round 3 cached these offsets in VGPRs and died for it). X path untouched.
// C/D = [d-col][batch]: h_prev re-read is 1 ds_read_b64, h write 1 b64.

typedef _Float16 half8 __attribute__((ext_vector_type(8)));
typedef __fp16  fp16x2 __attribute__((ext_vector_type(2)));
typedef __fp16  fp16x4 __attribute__((ext_vector_type(4)));
typedef float    f32x4 __attribute__((ext_vector_type(4)));

#define MFMA(a, b, c) __builtin_amdgcn_mfma_f32_16x16x32_f16((a), (b), (c), 0, 0, 0)

constexpr int T_STEPS = 25;
constexpr int D = 128;
constexpr int NG = 384;   // 3*D
constexpr int BT = 64;    // batch rows per block
constexpr int SX = 132;   // f32 row stride for X (round-0 layout, unchanged)

typedef const __attribute__((address_space(1))) unsigned int guint;
typedef __attribute__((address_space(3))) unsigned int luint;

__device__ __forceinline__ void load_lds4(const float* g, float* l) {
    // one dword per lane, LDS dest = wave-uniform base + lane*4
    __builtin_amdgcn_global_load_lds((guint*)(uintptr_t)g, (luint*)l, 4, 0, 0);
}

__device__ __forceinline__ float sigm(float v) {
    return __builtin_amdgcn_rcpf(1.0f + __expf(-v));
}

__device__ __forceinline__ half8 pkrtz8(const f32x4 v0, const f32x4 v1) {
    union { fp16x2 h2[4]; half8 h8; } u;
    u.h2[0] = __builtin_amdgcn_cvt_pkrtz(v0.x, v0.y);
    u.h2[1] = __builtin_amdgcn_cvt_pkrtz(v0.z, v0.w);
    u.h2[2] = __builtin_amdgcn_cvt_pkrtz(v1.x, v1.y);
    u.h2[3] = __builtin_amdgcn_cvt_pkrtz(v1.z, v1.w);
    return u.h8;
}

__global__ __attribute__((amdgpu_flat_work_group_size(1024, 1024),
                          amdgpu_waves_per_eu(4, 4)))
void gru2_kernel(
    const float* __restrict__ x, const float* __restrict__ W1,
    const float* __restrict__ U1, const float* __restrict__ W2,
    const float* __restrict__ U2, const float* __restrict__ Wout,
    float* __restrict__ out) {
    __shared__ float    X[2][BT * SX];   // x_t f32 staging, double-buffered (67.6 KB)
    __shared__ _Float16 H1[2][BT * D];   // h1 state, swizzled, dbuf (32.8 KB)
    __shared__ _Float16 H2[2][BT * D];   // h2 state, swizzled, dbuf (32.8 KB)

    const int tid = threadIdx.x;
    const int w = tid >> 6, lane = tid & 63, l15 = lane & 15, quad = lane >> 4;
    const int layer = w >> 3;       // 0: layer1 waves, 1: layer2 waves
    const int d0 = (w & 7) * 16;    // this wave's 16-col d-slice per gate
    const int b0 = blockIdx.x * BT;

    // ---- one-time: this wave's [W;U] fragments as MFMA *A* operand ----
    // A-frag (16x16x32): lane holds A[m = l15][k = quad*8 + e]; element =
    // Wgt[k][gate*128 + d0 + l15]. k-tiles 0..3 = W rows, 4..7 = U rows.
    half8 wg[3][8];
    {
        const float* Wp = layer ? W2 : W1;
        const float* Up = layer ? U2 : U1;
#pragma unroll
        for (int g = 0; g < 3; ++g) {
            const int c = g * 128 + d0 + l15;
#pragma unroll
            for (int kt = 0; kt < 8; ++kt) {
                const float* src = (kt < 4 ? Wp : Up) + (size_t)((kt & 3) * 32 + quad * 8) * NG + c;
                half8 f;
#pragma unroll
                for (int e = 0; e < 8; ++e) f[e] = (_Float16)src[(size_t)e * NG];
                wg[g][kt] = f;
            }
        }
    }

    // zero initial states: L1 reads H1[0] at iter 0; L2 reads H2[1] at iter 1
    // (zeros are layout-invariant, plain linear fill)
    for (int idx = tid; idx < BT * D; idx += 1024) {
        H1[0][idx] = (_Float16)0.f;
        H2[1][idx] = (_Float16)0.f;
    }

    // prologue: DMA x(t=0) into X[0]: 128 lane-dword chunks, 8 per wave
#pragma unroll
    for (int r8 = 0; r8 < 8; ++r8) {
        const int idx = w * 8 + r8, row = idx >> 1, hf = (idx & 1) * 64;
        load_lds4(x + ((size_t)(b0 + row) * T_STEPS + 0) * D + hf + lane,
                  &X[0][row * SX + hf]);
    }
    __syncthreads();  // drains DMA (vmcnt(0) before s_barrier)

#pragma unroll 1
    for (int it = 0; it <= T_STEPS; ++it) {
        const int p = it & 1, q = p ^ 1;
        // issue DMA for x(it+1) -> X[q]; overlaps this iteration's compute.
        // X[q] readers finished at the barrier ending iter it-1.
        if (it + 1 < T_STEPS) {
#pragma unroll
            for (int r8 = 0; r8 < 8; ++r8) {
                const int idx = w * 8 + r8, row = idx >> 1, hf = (idx & 1) * 64;
                load_lds4(x + ((size_t)(b0 + row) * T_STEPS + (it + 1)) * D + hf + lane,
                          &X[q][row * SX + hf]);
            }
        }
        const bool active = layer ? (it >= 1) : (it < T_STEPS);
        if (active) {
            const _Float16* Hst = layer ? H2[p] : H1[p];  // own state (h_prev)
            _Float16* Hout      = layer ? H2[q] : H1[q];  // own state dest
            const _Float16* Hin = H1[p];                  // layer-2 input = h1
            const float* Xin    = X[p];                   // layer-1 input = x_t
#pragma unroll
            for (int nt = 0; nt < 4; ++nt) {
                const int bb = nt * 16 + l15;             // batch row (B-frag n)
                const int rowb = bb * D;                  // f16 row base
                // swizzled fragment base: chunk (quad ^ l15); kt flips via XOR
                const int Ab = rowb + ((quad ^ l15) << 3);
                f32x4 cz = {0.f, 0.f, 0.f, 0.f}, cr = {0.f, 0.f, 0.f, 0.f};
                f32x4 cxh = {0.f, 0.f, 0.f, 0.f}, cuh = {0.f, 0.f, 0.f, 0.f};
                if (!layer) {
                    const float* bx = Xin + bb * SX + quad * 8;
#pragma unroll
                    for (int kt = 0; kt < 4; ++kt) {  // input part (W): x_t f32
                        const f32x4 v0 = *(const f32x4*)(bx + kt * 32);
                        const f32x4 v1 = *(const f32x4*)(bx + kt * 32 + 4);
                        const half8 B = pkrtz8(v0, v1);
                        cz  = MFMA(wg[0][kt], B, cz);
                        cr  = MFMA(wg[1][kt], B, cr);
                        cxh = MFMA(wg[2][kt], B, cxh);
                    }
                } else {
#pragma unroll
                    for (int kt = 0; kt < 4; ++kt) {  // input part (W): h1 f16
                        const half8 B = *(const half8*)(Hin + (Ab ^ (kt << 5)));
                        cz  = MFMA(wg[0][kt], B, cz);
                        cr  = MFMA(wg[1][kt], B, cr);
                        cxh = MFMA(wg[2][kt], B, cxh);
                    }
                }
                {
#pragma unroll
                    for (int kt = 0; kt < 4; ++kt) {  // state part (U): h_prev
                        const half8 B = *(const half8*)(Hst + (Ab ^ (kt << 5)));
                        cz  = MFMA(wg[0][4 + kt], B, cz);
                        cr  = MFMA(wg[1][4 + kt], B, cr);
                        cuh = MFMA(wg[2][4 + kt], B, cuh);
                    }
                }
                // C/D: col(N)=l15 -> batch bb; row(M)=quad*4+i2 -> d0+quad*4+i2
                // swizzled h-slot: chunk ((d0+quad*4)>>3) ^ l15, sub-off (quad&1)*4
                const int hoff = rowb +
                    (((((d0 >> 3) + (quad >> 1))) ^ l15) << 3) + (quad & 1) * 4;
                const fp16x4 hp4 = *(const fp16x4*)(Hst + hoff);
                fp16x4 hn4;
#pragma unroll
                for (int i2 = 0; i2 < 4; ++i2) {
                    const float z = sigm(cz[i2]);
                    const float r = sigm(cr[i2]);
                    const float hh = cxh[i2] + r * cuh[i2];
                    hn4[i2] = (__fp16)(hh + z * ((float)hp4[i2] - hh));
                }
                *(fp16x4*)(Hout + hoff) = hn4;
            }
        }
        __syncthreads();
    }

    // ---- epilogue: out = h2(T-1) @ Wout; h2 is in H2[0] (swizzled). Flipped
    // operands: A = Wout^T (regs), B = h2 (LDS). Waves 8-15, 16 out-cols each.
    if (layer) {
        half8 wO[4];
#pragma unroll
        for (int kt = 0; kt < 4; ++kt) {
            half8 f;
#pragma unroll
            for (int e = 0; e < 8; ++e)
                f[e] = (_Float16)Wout[(size_t)(kt * 32 + quad * 8 + e) * D + d0 + l15];
            wO[kt] = f;
        }
#pragma unroll
        for (int nt = 0; nt < 4; ++nt) {
            const int Ab = (nt * 16 + l15) * D + ((quad ^ l15) << 3);
            f32x4 acc = {0.f, 0.f, 0.f, 0.f};
#pragma unroll
            for (int kt = 0; kt < 4; ++kt)
                acc = MFMA(wO[kt], *(const half8*)(H2[0] + (Ab ^ (kt << 5))), acc);
            *(f32x4*)(out + (size_t)(b0 + nt * 16 + l15) * D + d0 + quad * 4) = acc;
        }
    }
}

extern "C" void kernel_launch(void* const* d_in, const int* in_sizes, int n_in,
                              void* d_out, int out_size, void* d_ws, size_t ws_size,
                              hipStream_t stream) {
    const float* x    = (const float*)d_in[0];
    const float* W1   = (const float*)d_in[1];
    const float* U1   = (const float*)d_in[2];
    const float* W2   = (const float*)d_in[3];
    const float* U2   = (const float*)d_in[4];
    const float* Wout = (const float*)d_in[5];
    gru2_kernel<<<dim3(16384 / BT), dim3(1024), 0, stream>>>(
        x, W1, U1, W2, U2, Wout, (float*)d_out);
}